// Round 6
// baseline (757.296 us; speedup 1.0000x reference)
//
#include <hip/hip_runtime.h>
#include <hip/hip_bf16.h>

// All external tensors are FLOAT32; bf16 is used only internally for MFMA.
typedef __bf16 bf16;
typedef __bf16 bfrag __attribute__((ext_vector_type(8)));   // 8 bf16 = 4 VGPRs (MFMA A/B)
typedef float f32x4 __attribute__((ext_vector_type(4)));    // MFMA C/D

constexpr int Bc = 4, Sc = 2048, Hc = 16, ADc = 64, HIDc = 1024;
constexpr size_t QKV_ELEMS = (size_t)Bc * Hc * Sc * ADc;    // 8388608 (16 MB bf16)

__device__ __forceinline__ void gload_lds16(const void* g, void* lds) {
  __builtin_amdgcn_global_load_lds(
      (const __attribute__((address_space(1))) unsigned int*)g,
      (__attribute__((address_space(3))) unsigned int*)lds, 16, 0, 0);
}

__device__ __forceinline__ bfrag ldb(const bf16* p) {
  return *(const bfrag*)p;
}

// ---------------------------------------------------------------------------
// fp32 -> bf16 conversion, 8 elements/thread.
// ---------------------------------------------------------------------------
__global__ __launch_bounds__(256) void f2b(const float* __restrict__ s,
                                           bf16* __restrict__ d) {
  const size_t i = ((size_t)blockIdx.x * 256 + threadIdx.x) * 8;
  const float4 a = *(const float4*)(s + i);
  const float4 b = *(const float4*)(s + i + 4);
  bfrag o = {(bf16)a.x, (bf16)a.y, (bf16)a.z, (bf16)a.w,
             (bf16)b.x, (bf16)b.y, (bf16)b.z, (bf16)b.w};
  *(bfrag*)(d + i) = o;
}

// ---------------------------------------------------------------------------
// GEMM C = A * B^T  (A:[M][K], Bm:[N][K], bf16 in, fp32 accum)
// MODE 0: A row-major; epilogue scatters bf16 Q(x0.125)/K/Vt(transposed)
// MODE 1: A in head-split layout [b][h][s][64]; fp32 store to Cf[M][Ndim]
// ---------------------------------------------------------------------------
template <int MODE>
__global__ __launch_bounds__(256) void gemm_bt(
    const bf16* __restrict__ A,
    const bf16* __restrict__ Bm,
    bf16* __restrict__ C0,
    bf16* __restrict__ C1,
    bf16* __restrict__ C2,
    float* __restrict__ Cf,
    int Kdim, int Ndim)
{
  __shared__ __align__(16) bf16 As[128 * 32];
  __shared__ __align__(16) bf16 Bs[128 * 32];

  const int tid  = threadIdx.x;
  const int wave = tid >> 6;
  const int lane = tid & 63;
  const int n16  = lane & 15;
  const int quad = lane >> 4;
  const int wm   = wave & 1;
  const int wn   = wave >> 1;
  const int m0   = blockIdx.y * 128;
  const int n0   = blockIdx.x * 128;

  const f32x4 fzero = {0.f, 0.f, 0.f, 0.f};
  f32x4 acc[4][4];
#pragma unroll
  for (int i = 0; i < 4; ++i)
#pragma unroll
    for (int j = 0; j < 4; ++j) acc[i][j] = fzero;

  const int lcol = (lane & 3) * 8;  // element offset within the 32-elem LDS row

  for (int k0 = 0; k0 < Kdim; k0 += 32) {
#pragma unroll
    for (int c = 0; c < 2; ++c) {
      const int chunk = wave * 2 + c;          // 0..7, 16 rows each
      const int row   = chunk * 16 + (lane >> 2);
      const bf16* agp;
      if (MODE == 0) {
        agp = A + (size_t)(m0 + row) * Kdim + k0 + lcol;
      } else {
        // A = O in head-split layout [b][h][s][64]; head h = k0>>6.
        const int gs = m0 + row;               // global row (b*2048 + s)
        const int h  = k0 >> 6;
        agp = A + (((size_t)(gs >> 11) * Hc + h) * Sc + (gs & 2047)) * ADc
                + (k0 & 63) + lcol;
      }
      gload_lds16(agp, (char*)As + chunk * 1024);
      gload_lds16(Bm + (size_t)(n0 + row) * Kdim + k0 + lcol,
                  (char*)Bs + chunk * 1024);
    }
    __syncthreads();

    bfrag af[4], bf[4];
#pragma unroll
    for (int i = 0; i < 4; ++i)
      af[i] = ldb(As + (wm * 64 + i * 16 + n16) * 32 + quad * 8);
#pragma unroll
    for (int j = 0; j < 4; ++j)
      bf[j] = ldb(Bs + (wn * 64 + j * 16 + n16) * 32 + quad * 8);
#pragma unroll
    for (int i = 0; i < 4; ++i)
#pragma unroll
      for (int j = 0; j < 4; ++j)
        acc[i][j] = __builtin_amdgcn_mfma_f32_16x16x32_bf16(af[i], bf[j], acc[i][j], 0, 0, 0);
    __syncthreads();
  }

#pragma unroll
  for (int i = 0; i < 4; ++i) {
    const int grow = m0 + wm * 64 + i * 16 + quad * 4;
#pragma unroll
    for (int j = 0; j < 4; ++j) {
      const int col_local = wn * 64 + j * 16 + n16;
#pragma unroll
      for (int r = 0; r < 4; ++r) {
        const int row = grow + r;
        const float v = acc[i][j][r];
        if (MODE == 1) {
          Cf[(size_t)row * Ndim + n0 + col_local] = v;   // fp32 final output
        } else {
          const int seg = n0 >> 10;               // 0=Q 1=K 2=V (uniform per block)
          const int hid = (n0 & 1023) + col_local;
          const int h = hid >> 6, a = hid & 63;
          const int bi = row >> 11, s = row & 2047;
          if (seg == 0)       // Q pre-scaled by 1/sqrt(64) (power of 2: exact)
            C0[(((size_t)bi * Hc + h) * Sc + s) * ADc + a] = (bf16)(v * 0.125f);
          else if (seg == 1)
            C1[(((size_t)bi * Hc + h) * Sc + s) * ADc + a] = (bf16)v;
          else                // V stored transposed: Vt[bh][a][s]
            C2[(((size_t)bi * Hc + h) * ADc + a) * Sc + s] = (bf16)v;
        }
      }
    }
  }
}

// ---------------------------------------------------------------------------
// Pack int32 mask -> 1 bit per element.
// ---------------------------------------------------------------------------
__global__ __launch_bounds__(256) void mask_pack(const int* __restrict__ mask,
                                                 unsigned* __restrict__ bits) {
  const int w = blockIdx.x * 256 + threadIdx.x;
  const int4* p = (const int4*)(mask + (size_t)w * 32);
  unsigned out = 0;
#pragma unroll
  for (int i = 0; i < 8; ++i) {
    int4 m = p[i];
    out |= (unsigned)(m.x != 0) << (i * 4);
    out |= (unsigned)(m.y != 0) << (i * 4 + 1);
    out |= (unsigned)(m.z != 0) << (i * 4 + 2);
    out |= (unsigned)(m.w != 0) << (i * 4 + 3);
  }
  bits[w] = out;
}

// ---------------------------------------------------------------------------
// Flash attention, flat softmax. Round-6 changes:
//  (a) XCD-locality swizzle: 1D grid (2048); bh = (lid>>8)*8 + (lid&7),
//      qt = (lid>>3)&31. All 32 q-tiles of one bh land on ONE XCD (lid mod 8
//      const) and arrive bh-by-bh => K/V working set ~1 MB per 4 MB L2
//      (was ~16 MB thrash -> every load from L3 at ~500 cyc).
//  (b) Register double-buffered K-prefetch: next tile's K-frags issued before
//      this tile's exp/LDS/PV phase, hiding residual L2 latency.
// ---------------------------------------------------------------------------
__global__ __launch_bounds__(256) void attn(
    const bf16* __restrict__ Qw,
    const bf16* __restrict__ Kw,
    const bf16* __restrict__ Vtw,
    const unsigned* __restrict__ mbits,
    bf16* __restrict__ Ow)   // == Qw (aliased)
{
  __shared__ __align__(16) bf16 Plds[4][16][72];  // +8 pad

  const int tid  = threadIdx.x;
  const int wave = tid >> 6, lane = tid & 63;
  const int n16  = lane & 15, quad = lane >> 4;
  const int lid  = blockIdx.x;
  const int qt   = (lid >> 3) & 31;
  const int bh   = ((lid >> 8) << 3) | (lid & 7);
  const int b    = bh >> 4;
  const int q0   = qt * 64 + wave * 16;

  // Q A-frags, resident all kernel (pre-scaled by 0.125 in gemm epilogue)
  const bf16* qrow = Qw + ((size_t)bh * Sc + q0 + n16) * ADc;
  const bfrag qf0 = ldb(qrow + quad * 8);
  const bfrag qf1 = ldb(qrow + 32 + quad * 8);

  const f32x4 fzero = {0.f, 0.f, 0.f, 0.f};
  float li[4] = {0.f, 0.f, 0.f, 0.f};   // per-lane partial denominators
  f32x4 of[4];
#pragma unroll
  for (int nt = 0; nt < 4; ++nt) of[nt] = fzero;

  const unsigned* mbase = mbits + ((size_t)b * Sc + q0 + quad * 4) * (Sc / 32);
  const bf16* kbase = Kw + ((size_t)bh * Sc + n16) * ADc + quad * 8;

  // prologue: K-frags for tile 0
  bfrag kf[4][2];
#pragma unroll
  for (int nt = 0; nt < 4; ++nt) {
    const bf16* krow = kbase + (size_t)(nt * 16) * ADc;
    kf[nt][0] = ldb(krow);
    kf[nt][1] = ldb(krow + 32);
  }

  for (int kt = 0; kt < Sc / 64; ++kt) {
    const int k0 = kt * 64;

    // S = Q K^T from pre-loaded kf
    f32x4 sf[4];
#pragma unroll
    for (int nt = 0; nt < 4; ++nt) {
      f32x4 c = fzero;
      c = __builtin_amdgcn_mfma_f32_16x16x32_bf16(qf0, kf[nt][0], c, 0, 0, 0);
      c = __builtin_amdgcn_mfma_f32_16x16x32_bf16(qf1, kf[nt][1], c, 0, 0, 0);
      sf[nt] = c;
    }

    // V B-frags issued early: vmcnt latency overlaps exp + LDS below.
    bfrag vf[4][2];
#pragma unroll
    for (int nt = 0; nt < 4; ++nt) {
      const bf16* vrow = Vtw + ((size_t)bh * ADc + nt * 16 + n16) * Sc + k0;
      vf[nt][0] = ldb(vrow + quad * 8);
      vf[nt][1] = ldb(vrow + 32 + quad * 8);
    }

    // K prefetch for next tile ((kt+1)&31 wraps to 0 on last iter: harmless)
    const int kn0 = ((kt + 1) & 31) * 64;
#pragma unroll
    for (int nt = 0; nt < 4; ++nt) {
      const bf16* krow = kbase + (size_t)(kn0 + nt * 16) * ADc;
      kf[nt][0] = ldb(krow);
      kf[nt][1] = ldb(krow + 32);
    }

    // mask words (broadcast within quad); applied AFTER exp.
    uint2 mw[4];
#pragma unroll
    for (int r = 0; r < 4; ++r)
      mw[r] = *(const uint2*)(mbase + (size_t)r * (Sc / 32) + kt * 2);

#pragma unroll
    for (int r = 0; r < 4; ++r) {
#pragma unroll
      for (int nt = 0; nt < 4; ++nt) {
        float p = __expf(sf[nt][r]);
        const unsigned word = (nt & 2) ? mw[r].y : mw[r].x;
        if ((word >> ((nt & 1) * 16 + n16)) & 1u) p = 0.f;
        sf[nt][r] = p;
        li[r] += p;
      }
    }

    // P: C-layout -> LDS -> A-layout (per-wave private region)
    bf16* pl = &Plds[wave][0][0];
    __asm__ volatile("" ::: "memory");
#pragma unroll
    for (int nt = 0; nt < 4; ++nt)
#pragma unroll
      for (int r = 0; r < 4; ++r)
        pl[(quad * 4 + r) * 72 + nt * 16 + n16] = (bf16)sf[nt][r];
    __asm__ volatile("" ::: "memory");
    const bfrag pf0 = ldb(pl + n16 * 72 + quad * 8);
    const bfrag pf1 = ldb(pl + n16 * 72 + 32 + quad * 8);

    // O += P * V
#pragma unroll
    for (int nt = 0; nt < 4; ++nt) {
      of[nt] = __builtin_amdgcn_mfma_f32_16x16x32_bf16(pf0, vf[nt][0], of[nt], 0, 0, 0);
      of[nt] = __builtin_amdgcn_mfma_f32_16x16x32_bf16(pf1, vf[nt][1], of[nt], 0, 0, 0);
    }
  }

  // epilogue: reduce li across the quad's 16 lanes (once), normalize, store
#pragma unroll
  for (int r = 0; r < 4; ++r) {
    float s = li[r];
    s += __shfl_xor(s, 1);
    s += __shfl_xor(s, 2);
    s += __shfl_xor(s, 4);
    s += __shfl_xor(s, 8);
    const float inv = 1.f / s;
    const int q = q0 + quad * 4 + r;
    bf16* orow = Ow + ((size_t)bh * Sc + q) * ADc;
#pragma unroll
    for (int nt = 0; nt < 4; ++nt)
      orow[nt * 16 + n16] = (bf16)(of[nt][r] * inv);
  }
}

extern "C" void kernel_launch(void* const* d_in, const int* in_sizes, int n_in,
                              void* d_out, int out_size, void* d_ws, size_t ws_size,
                              hipStream_t stream) {
  const float* iQ = (const float*)d_in[0];
  const int* mask = (const int*)d_in[1];
  const float* Wa = (const float*)d_in[2];
  const float* Wo = (const float*)d_in[3];
  float* out      = (float*)d_out;   // 8.4M fp32 = 32 MB

  // d_out doubles as scratch until the final GEMM overwrites all of it:
  bf16* iQb       = (bf16*)d_out;                     // 16 MB
  bf16* Wab       = iQb + QKV_ELEMS;                  // 6 MB
  unsigned* mbits = (unsigned*)(Wab + 3145728);       // 2 MB
  // Workspace (50 MB): Q/O share a buffer; Wob read by the final GEMM.
  bf16* Qw  = (bf16*)d_ws;        // 16 MB (Q, then O)
  bf16* Kw  = Qw + QKV_ELEMS;     // 16 MB
  bf16* Vtw = Kw + QKV_ELEMS;     // 16 MB
  bf16* Wob = Vtw + QKV_ELEMS;    // 2 MB

  f2b<<<dim3(8388608 / 2048), 256, 0, stream>>>(iQ, iQb);
  f2b<<<dim3(3145728 / 2048), 256, 0, stream>>>(Wa, Wab);
  f2b<<<dim3(1048576 / 2048), 256, 0, stream>>>(Wo, Wob);
  mask_pack<<<dim3((Bc * Sc * Sc / 32) / 256), 256, 0, stream>>>(mask, mbits);
  gemm_bt<0><<<dim3(24, 64), 256, 0, stream>>>(iQb, Wab, Qw, Kw, Vtw, nullptr, 1024, 3072);
  attn<<<dim3(Bc * Hc * (Sc / 64)), 256, 0, stream>>>(Qw, Kw, Vtw, mbits, Qw);
  gemm_bt<1><<<dim3(8, 64), 256, 0, stream>>>(Qw, Wob, nullptr, nullptr, nullptr, out, 1024, 1024);
}

// Round 7
// 401.477 us; speedup vs baseline: 1.8863x; 1.8863x over previous
//
#include <hip/hip_runtime.h>
#include <hip/hip_bf16.h>

// All external tensors are FLOAT32; bf16 is used only internally for MFMA.
typedef __bf16 bf16;
typedef __bf16 bfrag __attribute__((ext_vector_type(8)));   // 8 bf16 = 4 VGPRs (MFMA A/B)
typedef float f32x4 __attribute__((ext_vector_type(4)));    // MFMA C/D

constexpr int Bc = 4, Sc = 2048, Hc = 16, ADc = 64, HIDc = 1024;
constexpr size_t QKV_ELEMS = (size_t)Bc * Hc * Sc * ADc;    // 8388608 (16 MB bf16)

__device__ __forceinline__ void gload_lds16(const void* g, void* lds) {
  __builtin_amdgcn_global_load_lds(
      (const __attribute__((address_space(1))) unsigned int*)g,
      (__attribute__((address_space(3))) unsigned int*)lds, 16, 0, 0);
}

__device__ __forceinline__ bfrag ldb(const bf16* p) {
  return *(const bfrag*)p;
}

// ---------------------------------------------------------------------------
// fp32 -> bf16 conversion, 8 elements/thread.
// ---------------------------------------------------------------------------
__global__ __launch_bounds__(256) void f2b(const float* __restrict__ s,
                                           bf16* __restrict__ d) {
  const size_t i = ((size_t)blockIdx.x * 256 + threadIdx.x) * 8;
  const float4 a = *(const float4*)(s + i);
  const float4 b = *(const float4*)(s + i + 4);
  bfrag o = {(bf16)a.x, (bf16)a.y, (bf16)a.z, (bf16)a.w,
             (bf16)b.x, (bf16)b.y, (bf16)b.z, (bf16)b.w};
  *(bfrag*)(d + i) = o;
}

// ---------------------------------------------------------------------------
// GEMM C = A * B^T  (A:[M][K], Bm:[N][K], bf16 in, fp32 accum)
// MODE 0: A row-major; epilogue scatters bf16 Q(x0.125)/K/Vt(transposed)
// MODE 1: A in head-split layout [b][h][s][64]; fp32 store to Cf[M][Ndim]
// ---------------------------------------------------------------------------
template <int MODE>
__global__ __launch_bounds__(256) void gemm_bt(
    const bf16* __restrict__ A,
    const bf16* __restrict__ Bm,
    bf16* __restrict__ C0,
    bf16* __restrict__ C1,
    bf16* __restrict__ C2,
    float* __restrict__ Cf,
    int Kdim, int Ndim)
{
  __shared__ __align__(16) bf16 As[128 * 32];
  __shared__ __align__(16) bf16 Bs[128 * 32];

  const int tid  = threadIdx.x;
  const int wave = tid >> 6;
  const int lane = tid & 63;
  const int n16  = lane & 15;
  const int quad = lane >> 4;
  const int wm   = wave & 1;
  const int wn   = wave >> 1;
  const int m0   = blockIdx.y * 128;
  const int n0   = blockIdx.x * 128;

  const f32x4 fzero = {0.f, 0.f, 0.f, 0.f};
  f32x4 acc[4][4];
#pragma unroll
  for (int i = 0; i < 4; ++i)
#pragma unroll
    for (int j = 0; j < 4; ++j) acc[i][j] = fzero;

  const int lcol = (lane & 3) * 8;  // element offset within the 32-elem LDS row

  for (int k0 = 0; k0 < Kdim; k0 += 32) {
#pragma unroll
    for (int c = 0; c < 2; ++c) {
      const int chunk = wave * 2 + c;          // 0..7, 16 rows each
      const int row   = chunk * 16 + (lane >> 2);
      const bf16* agp;
      if (MODE == 0) {
        agp = A + (size_t)(m0 + row) * Kdim + k0 + lcol;
      } else {
        // A = O in head-split layout [b][h][s][64]; head h = k0>>6.
        const int gs = m0 + row;               // global row (b*2048 + s)
        const int h  = k0 >> 6;
        agp = A + (((size_t)(gs >> 11) * Hc + h) * Sc + (gs & 2047)) * ADc
                + (k0 & 63) + lcol;
      }
      gload_lds16(agp, (char*)As + chunk * 1024);
      gload_lds16(Bm + (size_t)(n0 + row) * Kdim + k0 + lcol,
                  (char*)Bs + chunk * 1024);
    }
    __syncthreads();

    bfrag af[4], bf[4];
#pragma unroll
    for (int i = 0; i < 4; ++i)
      af[i] = ldb(As + (wm * 64 + i * 16 + n16) * 32 + quad * 8);
#pragma unroll
    for (int j = 0; j < 4; ++j)
      bf[j] = ldb(Bs + (wn * 64 + j * 16 + n16) * 32 + quad * 8);
#pragma unroll
    for (int i = 0; i < 4; ++i)
#pragma unroll
      for (int j = 0; j < 4; ++j)
        acc[i][j] = __builtin_amdgcn_mfma_f32_16x16x32_bf16(af[i], bf[j], acc[i][j], 0, 0, 0);
    __syncthreads();
  }

#pragma unroll
  for (int i = 0; i < 4; ++i) {
    const int grow = m0 + wm * 64 + i * 16 + quad * 4;
#pragma unroll
    for (int j = 0; j < 4; ++j) {
      const int col_local = wn * 64 + j * 16 + n16;
#pragma unroll
      for (int r = 0; r < 4; ++r) {
        const int row = grow + r;
        const float v = acc[i][j][r];
        if (MODE == 1) {
          Cf[(size_t)row * Ndim + n0 + col_local] = v;   // fp32 final output
        } else {
          const int seg = n0 >> 10;               // 0=Q 1=K 2=V (uniform per block)
          const int hid = (n0 & 1023) + col_local;
          const int h = hid >> 6, a = hid & 63;
          const int bi = row >> 11, s = row & 2047;
          if (seg == 0)       // Q pre-scaled by 1/sqrt(64) (power of 2: exact)
            C0[(((size_t)bi * Hc + h) * Sc + s) * ADc + a] = (bf16)(v * 0.125f);
          else if (seg == 1)
            C1[(((size_t)bi * Hc + h) * Sc + s) * ADc + a] = (bf16)v;
          else                // V stored transposed: Vt[bh][a][s]
            C2[(((size_t)bi * Hc + h) * ADc + a) * Sc + s] = (bf16)v;
        }
      }
    }
  }
}

// ---------------------------------------------------------------------------
// Pack int32 mask -> 1 bit per element.
// ---------------------------------------------------------------------------
__global__ __launch_bounds__(256) void mask_pack(const int* __restrict__ mask,
                                                 unsigned* __restrict__ bits) {
  const int w = blockIdx.x * 256 + threadIdx.x;
  const int4* p = (const int4*)(mask + (size_t)w * 32);
  unsigned out = 0;
#pragma unroll
  for (int i = 0; i < 8; ++i) {
    int4 m = p[i];
    out |= (unsigned)(m.x != 0) << (i * 4);
    out |= (unsigned)(m.y != 0) << (i * 4 + 1);
    out |= (unsigned)(m.z != 0) << (i * 4 + 2);
    out |= (unsigned)(m.w != 0) << (i * 4 + 3);
  }
  bits[w] = out;
}

// ---------------------------------------------------------------------------
// Flash attention, flat softmax, BLOCK-staged K/V (round-7 rewrite).
// 512 threads = 8 waves; block owns 128 q-rows of one bh. Per 64-key tile,
// K (64x64) and V^T (64x64) are staged once into padded LDS and shared by
// all 8 waves (8x fewer global loads than per-wave frags). The next tile is
// prefetched into 8 VGPRs/thread during compute (m97 2-barrier loop), so
// global latency is off the critical path. All MFMA operands come from LDS.
// LDS layouts [64][72] (+8 pad): store & frag-read patterns are 2-way max
// (free). P roundtrip per-wave private as before. O overwrites Q (safe:
// each wave reads its own Q rows into regs first).
// ---------------------------------------------------------------------------
__global__ __launch_bounds__(512) void attn(
    const bf16* __restrict__ Qw,
    const bf16* __restrict__ Kw,
    const bf16* __restrict__ Vtw,
    const unsigned* __restrict__ mbits,
    bf16* __restrict__ Ow)   // == Qw (aliased)
{
  __shared__ __align__(16) bf16 Ks[64 * 72];        // [key][dim]
  __shared__ __align__(16) bf16 Vs[64 * 72];        // [dim][key]
  __shared__ __align__(16) bf16 Plds[8][16][72];

  const int tid  = threadIdx.x;
  const int wave = tid >> 6, lane = tid & 63;
  const int n16  = lane & 15, quad = lane >> 4;
  const int bh   = blockIdx.x >> 4, qb = blockIdx.x & 15;
  const int b    = bh >> 4;
  const int q0   = qb * 128 + wave * 16;

  // staging coords: thread t -> row t/8, 8-elem chunk (t%8)*8
  const int srow = tid >> 3;
  const int scol = (tid & 7) * 8;
  const bf16* gK = Kw  + ((size_t)bh * Sc + srow) * ADc + scol;  // +k0*ADc per tile
  const bf16* gV = Vtw + ((size_t)bh * ADc + srow) * Sc + scol;  // +k0 per tile
  bf16* lK = Ks + srow * 72 + scol;
  bf16* lV = Vs + srow * 72 + scol;

  // Q A-frags, resident all kernel (pre-scaled by 0.125 in gemm epilogue)
  const bf16* qrow = Qw + ((size_t)bh * Sc + q0 + n16) * ADc;
  const bfrag qf0 = ldb(qrow + quad * 8);
  const bfrag qf1 = ldb(qrow + 32 + quad * 8);

  const f32x4 fzero = {0.f, 0.f, 0.f, 0.f};
  float li[4] = {0.f, 0.f, 0.f, 0.f};
  f32x4 of[4];
#pragma unroll
  for (int nt = 0; nt < 4; ++nt) of[nt] = fzero;

  const unsigned* mbase = mbits + ((size_t)b * Sc + q0 + quad * 4) * (Sc / 32);

  // stage tile 0
  {
    bfrag k0r = ldb(gK);
    bfrag v0r = ldb(gV);
    *(bfrag*)lK = k0r;
    *(bfrag*)lV = v0r;
  }
  __syncthreads();

  for (int kt = 0; kt < Sc / 64; ++kt) {
    // prefetch tile kt+1 into regs (wraps on last iter: harmless)
    const int kn0 = ((kt + 1) & 31) * 64;
    const bfrag kpre = ldb(gK + (size_t)kn0 * ADc);
    const bfrag vpre = ldb(gV + kn0);

    // mask words early (broadcast within quad)
    uint2 mw[4];
#pragma unroll
    for (int r = 0; r < 4; ++r)
      mw[r] = *(const uint2*)(mbase + (size_t)r * (Sc / 32) + kt * 2);

    // S = Q K^T from LDS K-frags
    f32x4 sf[4];
#pragma unroll
    for (int nt = 0; nt < 4; ++nt) {
      const bf16* kr = Ks + (nt * 16 + n16) * 72 + quad * 8;
      const bfrag kf0 = ldb(kr);
      const bfrag kf1 = ldb(kr + 32);
      f32x4 c = fzero;
      c = __builtin_amdgcn_mfma_f32_16x16x32_bf16(qf0, kf0, c, 0, 0, 0);
      c = __builtin_amdgcn_mfma_f32_16x16x32_bf16(qf1, kf1, c, 0, 0, 0);
      sf[nt] = c;
    }

    // exp + mask (after exp: load latency overlapped) + per-lane denominator
#pragma unroll
    for (int r = 0; r < 4; ++r) {
#pragma unroll
      for (int nt = 0; nt < 4; ++nt) {
        float p = __expf(sf[nt][r]);
        const unsigned word = (nt & 2) ? mw[r].y : mw[r].x;
        if ((word >> ((nt & 1) * 16 + n16)) & 1u) p = 0.f;
        sf[nt][r] = p;
        li[r] += p;
      }
    }

    // P: C-layout -> LDS -> A-layout (per-wave private region)
    bf16* pl = &Plds[wave][0][0];
    __asm__ volatile("" ::: "memory");
#pragma unroll
    for (int nt = 0; nt < 4; ++nt)
#pragma unroll
      for (int r = 0; r < 4; ++r)
        pl[(quad * 4 + r) * 72 + nt * 16 + n16] = (bf16)sf[nt][r];
    __asm__ volatile("" ::: "memory");
    const bfrag pf0 = ldb(pl + n16 * 72 + quad * 8);
    const bfrag pf1 = ldb(pl + n16 * 72 + 32 + quad * 8);

    // O += P * V from LDS V-frags
#pragma unroll
    for (int nt = 0; nt < 4; ++nt) {
      const bf16* vr = Vs + (nt * 16 + n16) * 72 + quad * 8;
      const bfrag vf0 = ldb(vr);
      const bfrag vf1 = ldb(vr + 32);
      of[nt] = __builtin_amdgcn_mfma_f32_16x16x32_bf16(pf0, vf0, of[nt], 0, 0, 0);
      of[nt] = __builtin_amdgcn_mfma_f32_16x16x32_bf16(pf1, vf1, of[nt], 0, 0, 0);
    }

    // swap in the prefetched tile
    __syncthreads();
    *(bfrag*)lK = kpre;
    *(bfrag*)lV = vpre;
    __syncthreads();
  }

  // epilogue: reduce li across the quad's 16 lanes (once), normalize, store
#pragma unroll
  for (int r = 0; r < 4; ++r) {
    float s = li[r];
    s += __shfl_xor(s, 1);
    s += __shfl_xor(s, 2);
    s += __shfl_xor(s, 4);
    s += __shfl_xor(s, 8);
    const float inv = 1.f / s;
    const int q = q0 + quad * 4 + r;
    bf16* orow = Ow + ((size_t)bh * Sc + q) * ADc;
#pragma unroll
    for (int nt = 0; nt < 4; ++nt)
      orow[nt * 16 + n16] = (bf16)(of[nt][r] * inv);
  }
}

extern "C" void kernel_launch(void* const* d_in, const int* in_sizes, int n_in,
                              void* d_out, int out_size, void* d_ws, size_t ws_size,
                              hipStream_t stream) {
  const float* iQ = (const float*)d_in[0];
  const int* mask = (const int*)d_in[1];
  const float* Wa = (const float*)d_in[2];
  const float* Wo = (const float*)d_in[3];
  float* out      = (float*)d_out;   // 8.4M fp32 = 32 MB

  // d_out doubles as scratch until the final GEMM overwrites all of it:
  bf16* iQb       = (bf16*)d_out;                     // 16 MB
  bf16* Wab       = iQb + QKV_ELEMS;                  // 6 MB
  unsigned* mbits = (unsigned*)(Wab + 3145728);       // 2 MB
  // Workspace (50 MB): Q/O share a buffer; Wob read by the final GEMM.
  bf16* Qw  = (bf16*)d_ws;        // 16 MB (Q, then O)
  bf16* Kw  = Qw + QKV_ELEMS;     // 16 MB
  bf16* Vtw = Kw + QKV_ELEMS;     // 16 MB
  bf16* Wob = Vtw + QKV_ELEMS;    // 2 MB

  f2b<<<dim3(8388608 / 2048), 256, 0, stream>>>(iQ, iQb);
  f2b<<<dim3(3145728 / 2048), 256, 0, stream>>>(Wa, Wab);
  f2b<<<dim3(1048576 / 2048), 256, 0, stream>>>(Wo, Wob);
  mask_pack<<<dim3((Bc * Sc * Sc / 32) / 256), 256, 0, stream>>>(mask, mbits);
  gemm_bt<0><<<dim3(24, 64), 256, 0, stream>>>(iQb, Wab, Qw, Kw, Vtw, nullptr, 1024, 3072);
  attn<<<dim3(Bc * Hc * 16), 512, 0, stream>>>(Qw, Kw, Vtw, mbits, Qw);
  gemm_bt<1><<<dim3(8, 64), 256, 0, stream>>>(Qw, Wob, nullptr, nullptr, nullptr, out, 1024, 1024);
}